// Round 11
// baseline (100.585 us; speedup 1.0000x reference)
//
#include <hip/hip_runtime.h>

typedef _Float16 half8 __attribute__((ext_vector_type(8)));
typedef float f32x4 __attribute__((ext_vector_type(4)));
typedef float f32x16 __attribute__((ext_vector_type(16)));

union H8 { half8 h; float4 f; };

#define EDIM 128
#define CDIM 128
#define HDIM 100
#define ODIM 104

// workspace offsets (bytes), 256-aligned
#define OFF_WIH    32768u      // wih B-frags (16x16x32):  2*21*4*64*8*2  = 172032
#define OFF_WHH    204800u     // whh B-frags (16x16x32):  2*21*4*64*8*2  = 172032
#define OFF_BIASP  376832u     // bias (bih + bhh_{r,z}; bih_n): 2*384*4  = 3072
#define OFF_STMT   379904u     // stmt f16 [t*64+b][128]:    4096*128*2   = 1048576

__device__ inline f32x4 zero4() { f32x4 z = {0.f, 0.f, 0.f, 0.f}; return z; }

// minimal-op transcendentals (guaranteed v_exp/v_rcp, no ocml fixup chains)
__device__ inline float fast_exp2(float x) {
  float r; asm("v_exp_f32 %0, %1" : "=v"(r) : "v"(x)); return r;
}
__device__ inline float fast_rcp(float x) {
  float r; asm("v_rcp_f32 %0, %1" : "=v"(r) : "v"(x)); return r;
}
__device__ inline float sigmoid_f(float x) {        // 1/(1+e^-x)
  return fast_rcp(1.f + fast_exp2(x * -1.44269504f));
}
__device__ inline float tanh_f(float x) {           // 1 - 2/(1+e^(2x))
  float e = fast_exp2(x * 2.88539008f);
  return fmaf(fast_rcp(1.f + e), -2.f, 1.f);
}

// K3 LDS swizzle: read 2-way-free AND write conflict-free
#define HSWZ(row) ((((row) & 3) << 4) ^ (((row) & 12) << 3))

// ---------------------------------------------------------------------------
// K1: per-block 4 trees (128 nodes). Blocks 0-86 additionally run the gru
//     weight prep slices. W_lin->frag conversion inline per block (L2-hot).
//     Ancestor walk overlapped into the GEMM1 phase (was its own barrier).
//     stmt stored in row' = t*64 + b order (tree g = b*64+t).
// ---------------------------------------------------------------------------
__global__ __launch_bounds__(256, 2) void astnn_tree(
    const int* __restrict__ node_ids, const int* __restrict__ parent,
    const float* __restrict__ emb, const float* __restrict__ W_lin,
    const float* __restrict__ b_lin,
    const float* __restrict__ wihf, const float* __restrict__ whhf,
    const float* __restrict__ bihf, const float* __restrict__ bhhf,
    const float* __restrict__ wihb, const float* __restrict__ whhb,
    const float* __restrict__ bihb, const float* __restrict__ bhhb,
    _Float16* __restrict__ wihfrag, _Float16* __restrict__ whhfrag,
    float* __restrict__ biasP, _Float16* __restrict__ stmt)
{
  __shared__ _Float16 ldsW[16384];   // 32KB: W_lin B-frags (built inline)
  __shared__ _Float16 ldsA[16384];   // 32KB: emb tile (swizzled), reused for h-frags
  __shared__ int ldsPar[128];
  __shared__ unsigned ldsAnc[128];

  const int t = threadIdx.x, blk = blockIdx.x;
  const int w = t >> 6, l = t & 63;
  const int base = blk * 128;

  // ---- gru prep slice (blocks 0-86): wih/whh frags + bias, global-only ----
  if (blk < 87) {
    int gid = blk * 256 + t;                 // 0..22271
    if (gid < 10752) {
      // wih -> 16x16x32 B-frags: N per-section 112 (21 tiles), K=128
      int i = gid, ll = i & 63, kc = (i >> 6) & 3;
      int rest = i >> 8, nt = rest % 21, d = rest / 21;
      const float* wih = d ? wihb : wihf;
      int n = (nt << 4) + (ll & 15), s = n / 112, j = n - 112 * s;
      int kb = (kc << 5) + ((ll >> 4) << 3);
#pragma unroll
      for (int e = 0; e < 8; e++) {
        int k = kb + e;
        float v = (j < HDIM) ? wih[(s * HDIM + j) * CDIM + k] : 0.f;
        wihfrag[i * 8 + e] = (_Float16)v;
      }
    } else if (gid < 21504) {
      // whh -> 16x16x32 B-frags: K padded to 128; k==HDIM (s==2) carries bhh_n
      int i = gid - 10752, ll = i & 63, kc = (i >> 6) & 3;
      int rest = i >> 8, nt = rest % 21, d = rest / 21;
      const float* whh = d ? whhb : whhf;
      const float* bhh = d ? bhhb : bhhf;
      int n = (nt << 4) + (ll & 15), s = n / 112, j = n - 112 * s;
      int kb = (kc << 5) + ((ll >> 4) << 3);
#pragma unroll
      for (int e = 0; e < 8; e++) {
        int k = kb + e;
        float v = 0.f;
        if (j < HDIM) {
          if (k < HDIM) v = whh[(s * HDIM + j) * HDIM + k];
          else if (k == HDIM && s == 2) v = bhh[2 * HDIM + j];
        }
        whhfrag[i * 8 + e] = (_Float16)v;
      }
    } else {
      // biasP[d][384] = bih[g] + (s<2 ? bhh[g] : 0), pad = 0
      int i = gid - 21504, d = i / 384, col = i % 384, s = col >> 7, j = col & 127;
      const float* bih = d ? bihb : bihf;
      const float* bhh = d ? bhhb : bhhf;
      float v = 0.f;
      if (j < HDIM) { v = bih[s * HDIM + j]; if (s < 2) v += bhh[s * HDIM + j]; }
      biasP[i] = v;
    }
  }

  if (t < 128) ldsPar[t] = parent[base + t] & 31;  // trees are 32-aligned globally

  {  // W_lin -> 16x16x32 B-frags directly into ldsW (L2-hot 64KB source)
#pragma unroll
    for (int i8 = 0; i8 < 8; i8++) {
      int fi = i8 * 256 + t;
      int ll = fi & 63, kc = (fi >> 6) & 3, nt = fi >> 8;
      int n = (nt << 4) + (ll & 15);
      int kb = (kc << 5) + ((ll >> 4) << 3);
      H8 u;
#pragma unroll
      for (int e = 0; e < 8; e++)
        u.h[e] = (_Float16)W_lin[(kb + e) * CDIM + n];
      *(float4*)&ldsW[fi * 8] = u.f;
    }
  }

  {  // gather embedding rows -> f16, swizzled row-major [128][128]
    const int r = t >> 1, hf = t & 1;
    const int nid = node_ids[base + r];
    const float4* erow = (const float4*)(emb + (size_t)nid * EDIM) + hf * 16;
#pragma unroll
    for (int b2 = 0; b2 < 2; b2++) {
      float4 stage[8];
#pragma unroll
      for (int i = 0; i < 8; i++) stage[i] = erow[b2 * 8 + i];
#pragma unroll
      for (int c4 = 0; c4 < 4; c4++) {
        H8 u;
#pragma unroll
        for (int e = 0; e < 8; e++)
          u.h[e] = (_Float16)(((const float*)&stage[0])[c4 * 8 + e]);
        int c = b2 * 4 + c4;
        int addr = (r * 256 + hf * 128 + c * 16) ^ ((r & 7) << 4);
        *(float4*)((char*)ldsA + addr) = u.f;
      }
    }
  }
  __syncthreads();   // emb tile + ldsPar ready

  // GEMM: h[128][128] = emb_tile @ W  (16x16x32 f16), wave w owns M-tiles 2w,2w+1
  f32x4 acc[2][8];
#pragma unroll
  for (int mt = 0; mt < 2; mt++)
#pragma unroll
    for (int nt = 0; nt < 8; nt++) acc[mt][nt] = zero4();
#pragma unroll
  for (int kc = 0; kc < 4; kc++) {
    half8 af[2];
#pragma unroll
    for (int mt = 0; mt < 2; mt++) {
      int row = (w * 2 + mt) * 16 + (l & 15);
      int addr = (row * 256 + (kc << 6) + ((l >> 4) << 4)) ^ ((row & 7) << 4);
      af[mt] = *(const half8*)((const char*)ldsA + addr);
    }
#pragma unroll
    for (int nt = 0; nt < 8; nt++) {
      half8 bf = *(const half8*)&ldsW[(((nt << 2) | kc) * 64 + l) * 8];
      acc[0][nt] = __builtin_amdgcn_mfma_f32_16x16x32_f16(af[0], bf, acc[0][nt], 0, 0, 0);
      acc[1][nt] = __builtin_amdgcn_mfma_f32_16x16x32_f16(af[1], bf, acc[1][nt], 0, 0, 0);
    }
  }
  // ancestor walk overlapped with GEMM1 drain (output needed only in GEMM2)
  if (t < 128) {
    int tree = t >> 5;
    unsigned mask = 0;
    int cur = t & 31;
#pragma unroll
    for (int it = 0; it < 11; ++it) { mask |= (1u << cur); cur = ldsPar[tree * 32 + cur]; }
    ldsAnc[t] = mask;
  }
  __syncthreads();  // all emb-tile reads done; ldsA reused for h-fragments

  // write h (+b_lin) into 32x32x16 B-frag layout: [tree][nt2][kc2][lane][8] f16
#pragma unroll
  for (int mt = 0; mt < 2; mt++) {
    const int Mt = w * 2 + mt, tree = Mt >> 1, kc2 = Mt & 1;
#pragma unroll
    for (int nt = 0; nt < 8; nt++) {
      const float bl = b_lin[nt * 16 + (l & 15)];
      const int nt2 = nt >> 1;
      const int ncol = ((nt & 1) << 4) + (l & 15);
#pragma unroll
      for (int reg = 0; reg < 4; reg++) {
        int rowrem = ((l >> 4) << 2) + reg;          // row within 16x16 C tile
        int l2 = ((rowrem >> 3) << 5) + ncol;
        int idx = (((((tree << 2) + nt2) << 1) + kc2) * 64 + l2) * 8 + (rowrem & 7);
        ldsA[idx] = (_Float16)(acc[mt][nt][reg] + bl);
      }
    }
  }
  __syncthreads();

  // per-tree subtree-sum: S[32][128] = anc(0/1) @ h  (32x32x16), wave w = tree w
  {
    const int tree = w;
    half8 ancf[2];
#pragma unroll
    for (int kc2 = 0; kc2 < 2; kc2++) {
      H8 u;
#pragma unroll
      for (int e = 0; e < 8; e++) {
        int n = (kc2 << 4) + ((l >> 5) << 3) + e;
        unsigned m = ldsAnc[(tree << 5) + n];
        u.h[e] = (_Float16)(float)((m >> (l & 31)) & 1u);
      }
      ancf[kc2] = u.h;
    }
    f32x16 acc2[4];
#pragma unroll
    for (int nt2 = 0; nt2 < 4; nt2++)
#pragma unroll
      for (int e = 0; e < 16; e++) acc2[nt2][e] = 0.f;
#pragma unroll
    for (int nt2 = 0; nt2 < 4; nt2++)
#pragma unroll
      for (int kc2 = 0; kc2 < 2; kc2++) {
        half8 bf = *(const half8*)&ldsA[(((((tree << 2) + nt2) << 1) + kc2) * 64 + l) * 8];
        acc2[nt2] = __builtin_amdgcn_mfma_f32_32x32x16_f16(ancf[kc2], bf, acc2[nt2], 0, 0, 0);
      }
    // max-pool over the 32 node rows -> stmt[row'][c], row' = t*64 + b
#pragma unroll
    for (int nt2 = 0; nt2 < 4; nt2++) {
      float m1 = acc2[nt2][0];
#pragma unroll
      for (int e = 1; e < 16; e++) m1 = fmaxf(m1, acc2[nt2][e]);
      m1 = fmaxf(m1, __shfl_xor(m1, 32));
      if (l < 32) {
        int g = blk * 4 + tree;                      // tree = b*64 + t
        int rowp = (g & 63) * 64 + (g >> 6);         // row' = t*64 + b
        stmt[(size_t)rowp * CDIM + (nt2 << 5) + l] = (_Float16)m1;
      }
    }
  }
}

// ---------------------------------------------------------------------------
// K3: bidirectional GRU with fused input GEMM (pipelined 1 step ahead) AND
//     fused FC epilogue. whh chain accumulates IN-PLACE into the consumed gi
//     registers (no acc copies). After the 64 steps each block writes pool to
//     LDS, computes its 16x104 partial out = pool @ fc_w[dir] (+fc_b on dir0)
//     and atomicAdds into out (out zeroed via hipMemsetAsync at call start).
//     Grid (4 mb, 2 dirs), 7 waves; wave w owns cols j=16w+(l&15).
//     bhh_n via constant h col 100 = 1.0 + whh k=100 carrier.
// ---------------------------------------------------------------------------
__global__ __launch_bounds__(448) void astnn_gru(
    const _Float16* __restrict__ whhfrag, const _Float16* __restrict__ wihfrag,
    const _Float16* __restrict__ stmt, const float* __restrict__ biasP,
    const float* __restrict__ fc_w, const float* __restrict__ fc_b,
    float* __restrict__ out)
{
  __shared__ _Float16 hlds[4096];  // 2 x (16 rows x 128 cols f16, swizzled)
  const int t = threadIdx.x, w = t >> 6, l = t & 63;
  const int mb = blockIdx.x, dir = blockIdx.y;
  for (int i = t; i < 512; i += 448)          // zero BOTH buffers
    ((float4*)hlds)[i] = make_float4(0.f, 0.f, 0.f, 0.f);
  __syncthreads();
  if (t < 32) {                               // h col 100 = 1.0 (bhh_n carrier)
    int row = t & 15, buf = t >> 4;
    int addr = ((row * 256 + 200) ^ HSWZ(row)) + (buf << 12);
    *(_Float16*)((char*)hlds + addr) = (_Float16)1.0f;
  }

  const int j = (w << 4) + (l & 15);
  const bool jv = (j < HDIM);
  const int rloc = (l >> 4) << 2;             // local row base: 0,4,8,12

  // hoisted LDS addresses (swizzle HSWZ)
  int raddr[4], waddr[4];
  {
    int row = l & 15;
#pragma unroll
    for (int kc = 0; kc < 4; kc++)
      raddr[kc] = (row * 256 + (kc << 6) + ((l >> 4) << 4)) ^ HSWZ(row);
#pragma unroll
    for (int reg = 0; reg < 4; reg++) {
      int rw = rloc + reg;
      waddr[reg] = (rw * 256 + (j << 1)) ^ HSWZ(rw);
    }
  }

  // weight B-frags: whh (hidden) and wih (input), same frag geometry
  half8 bfr[3][4], bfw[3][4];
  {
    const half8* wfh = (const half8*)whhfrag + dir * 5376;
    const half8* wfi = (const half8*)wihfrag + dir * 5376;
#pragma unroll
    for (int s = 0; s < 3; s++)
#pragma unroll
      for (int kc = 0; kc < 4; kc++) {
        int idx = (((s * 7 + w) << 2) + kc) * 64 + l;
        bfr[s][kc] = wfh[idx];
        bfw[s][kc] = wfi[idx];
      }
  }
  const float bias0 = biasP[dir * 384 + j];
  const float bias1 = biasP[dir * 384 + 128 + j];
  const float bias2 = biasP[dir * 384 + 256 + j];

  // stmt slab loads: lane-fixed byte offsets + SALU-stepped t pointer
  int soff[4];
#pragma unroll
  for (int kc = 0; kc < 4; kc++)
    soff[kc] = (((mb << 4) + (l & 15)) * 256) + (kc << 6) + ((l >> 4) << 4);
  const ptrdiff_t sstep = dir ? -16384 : 16384;   // 64 rows * 256B per t
  const char* sbase = (const char*)stmt + (size_t)(dir ? 63 : 0) * 16384;

  half8 sfA[4], sfB[4];
#pragma unroll
  for (int kc = 0; kc < 4; kc++) sfA[kc] = *(const half8*)(sbase + soff[kc]);
  const char* spre = sbase + sstep;
#pragma unroll
  for (int kc = 0; kc < 4; kc++) sfB[kc] = *(const half8*)(spre + soff[kc]);
  spre += sstep;

  // prologue: giA = bias + wih @ stmt[t0]
  f32x4 giA[3], giB[3];
  giA[0] = f32x4{bias0, bias0, bias0, bias0};
  giA[1] = f32x4{bias1, bias1, bias1, bias1};
  giA[2] = f32x4{bias2, bias2, bias2, bias2};
#pragma unroll
  for (int kc = 0; kc < 4; kc++) {
    giA[0] = __builtin_amdgcn_mfma_f32_16x16x32_f16(sfA[kc], bfw[0][kc], giA[0], 0, 0, 0);
    giA[1] = __builtin_amdgcn_mfma_f32_16x16x32_f16(sfA[kc], bfw[1][kc], giA[1], 0, 0, 0);
    giA[2] = __builtin_amdgcn_mfma_f32_16x16x32_f16(sfA[kc], bfw[2][kc], giA[2], 0, 0, 0);
  }

  float hreg[4], pool[4];
#pragma unroll
  for (int i = 0; i < 4; i++) { hreg[i] = 0.f; pool[i] = -3.0e38f; }
  __syncthreads();

  // GIC: gi consumed this step (whh accumulates IN-PLACE into GIC[0..1]).
  // GIN: gi computed for next step from SFsrc. SFdst: prefetch target.
#define GRU_BODY(GIC, GIN, SFsrc, SFdst, ROFF, WOFF, CN, PF)                    \
  {                                                                             \
    half8 afh[4];                                                               \
    _Pragma("unroll")                                                           \
    for (int kc = 0; kc < 4; kc++)                                              \
      afh[kc] = *(const half8*)((const char*)hlds + raddr[kc] + (ROFF));        \
    f32x4 acc2h = zero4();                                                      \
    _Pragma("unroll")  /* critical whh chain FIRST, in-place into GIC */        \
    for (int kc = 0; kc < 4; kc++) {                                            \
      GIC[0] = __builtin_amdgcn_mfma_f32_16x16x32_f16(afh[kc], bfr[0][kc], GIC[0], 0, 0, 0); \
      GIC[1] = __builtin_amdgcn_mfma_f32_16x16x32_f16(afh[kc], bfr[1][kc], GIC[1], 0, 0, 0); \
      acc2h  = __builtin_amdgcn_mfma_f32_16x16x32_f16(afh[kc], bfr[2][kc], acc2h, 0, 0, 0);  \
    }                                                                           \
    if (CN) {  /* independent next-step gi chain: fills whh->gates latency */   \
      GIN[0] = f32x4{bias0, bias0, bias0, bias0};                               \
      GIN[1] = f32x4{bias1, bias1, bias1, bias1};                               \
      GIN[2] = f32x4{bias2, bias2, bias2, bias2};                               \
      _Pragma("unroll")                                                         \
      for (int kc = 0; kc < 4; kc++) {                                          \
        GIN[0] = __builtin_amdgcn_mfma_f32_16x16x32_f16(SFsrc[kc], bfw[0][kc], GIN[0], 0, 0, 0); \
        GIN[1] = __builtin_amdgcn_mfma_f32_16x16x32_f16(SFsrc[kc], bfw[1][kc], GIN[1], 0, 0, 0); \
        GIN[2] = __builtin_amdgcn_mfma_f32_16x16x32_f16(SFsrc[kc], bfw[2][kc], GIN[2], 0, 0, 0); \
      }                                                                         \
    }                                                                           \
    if (PF) {                                                                   \
      SFdst[0] = *(const half8*)(spre + soff[0]);                               \
      SFdst[1] = *(const half8*)(spre + soff[1]);                               \
      SFdst[2] = *(const half8*)(spre + soff[2]);                               \
      SFdst[3] = *(const half8*)(spre + soff[3]);                               \
      spre += sstep;                                                            \
    }                                                                           \
    _Pragma("unroll")                                                           \
    for (int reg = 0; reg < 4; reg++) {                                         \
      float r = sigmoid_f(GIC[0][reg]);                                         \
      float z = sigmoid_f(GIC[1][reg]);                                         \
      float n = tanh_f(fmaf(r, acc2h[reg], GIC[2][reg]));                       \
      float hn = n + z * (hreg[reg] - n);                                       \
      hreg[reg] = hn;                                                           \
      pool[reg] = fmaxf(pool[reg], hn);                                         \
      if (jv)                                                                   \
        *(_Float16*)((char*)hlds + waddr[reg] + (WOFF)) = (_Float16)hn;         \
    }                                                                           \
    asm volatile("s_waitcnt lgkmcnt(0)" ::: "memory");                          \
    __builtin_amdgcn_s_barrier();                                               \
    __builtin_amdgcn_sched_barrier(0);                                          \
  }

#pragma unroll 1
  for (int it = 0; it < 31; ++it) {
    GRU_BODY(giA, giB, sfB, sfA, 0, 4096, 1, 1)       // even step 2it
    GRU_BODY(giB, giA, sfA, sfB, 4096, 0, 1, 1)       // odd  step 2it+1
  }
  GRU_BODY(giA, giB, sfB, sfA, 0, 4096, 1, 0)         // step 62
  GRU_BODY(giB, giA, sfA, sfB, 4096, 0, 0, 0)         // step 63
#undef GRU_BODY

  // ---- fused FC epilogue: partial out[16 x 104] from this block's pool ----
  float* pl = (float*)hlds;                   // [112 cols][16 rows] f32 = 7168B
  if (jv) {
    float4 v = make_float4(pool[0], pool[1], pool[2], pool[3]);
    *(float4*)(pl + j * 16 + rloc) = v;       // rows rloc..rloc+3, col j
  }
  __syncthreads();
  {
    const float* fcw = fc_w + (size_t)dir * HDIM * ODIM;
    for (int i = t; i < 16 * ODIM; i += 448) {
      int row = i / ODIM, o = i - row * ODIM;
      float s = dir ? 0.f : fc_b[o];
#pragma unroll 4
      for (int k = 0; k < HDIM; k++)
        s = fmaf(pl[k * 16 + row], fcw[k * ODIM + o], s);
      atomicAdd(&out[(size_t)((mb << 4) + row) * ODIM + o], s);
    }
  }
}

// ---------------------------------------------------------------------------
extern "C" void kernel_launch(void* const* d_in, const int* in_sizes, int n_in,
                              void* d_out, int out_size, void* d_ws, size_t ws_size,
                              hipStream_t stream)
{
  const int* node_ids = (const int*)d_in[0];
  const int* parent   = (const int*)d_in[1];
  // d_in[2]=level, d_in[3]=tree_id: unused (decreasing-index order suffices)
  const float* emb    = (const float*)d_in[4];
  const float* W_lin  = (const float*)d_in[5];
  const float* b_lin  = (const float*)d_in[6];
  const float* wihf   = (const float*)d_in[7];
  const float* whhf   = (const float*)d_in[8];
  const float* bihf   = (const float*)d_in[9];
  const float* bhhf   = (const float*)d_in[10];
  const float* wihb   = (const float*)d_in[11];
  const float* whhb   = (const float*)d_in[12];
  const float* bihb   = (const float*)d_in[13];
  const float* bhhb   = (const float*)d_in[14];
  const float* fc_w   = (const float*)d_in[15];
  const float* fc_b   = (const float*)d_in[16];

  char* ws = (char*)d_ws;
  _Float16* wihfrag = (_Float16*)(ws + OFF_WIH);
  _Float16* whhfrag = (_Float16*)(ws + OFF_WHH);
  float* biasP      = (float*)(ws + OFF_BIASP);
  _Float16* stmt    = (_Float16*)(ws + OFF_STMT);
  float* out        = (float*)d_out;

  hipMemsetAsync(d_out, 0, (size_t)out_size * sizeof(float), stream);
  astnn_tree<<<1024, 256, 0, stream>>>(node_ids, parent, emb, W_lin, b_lin,
                                       wihf, whhf, bihf, bhhf,
                                       wihb, whhb, bihb, bhhb,
                                       wihfrag, whhfrag, biasP, stmt);
  astnn_gru<<<dim3(4, 2), 448, 0, stream>>>(whhfrag, wihfrag, stmt, biasP,
                                            fc_w, fc_b, out);
}

// Round 12
// 100.438 us; speedup vs baseline: 1.0015x; 1.0015x over previous
//
#include <hip/hip_runtime.h>

typedef _Float16 half8 __attribute__((ext_vector_type(8)));
typedef float f32x4 __attribute__((ext_vector_type(4)));
typedef float f32x16 __attribute__((ext_vector_type(16)));

union H8 { half8 h; float4 f; };

#define EDIM 128
#define CDIM 128
#define HDIM 100
#define ODIM 104

// workspace offsets (bytes), 256-aligned
#define OFF_WIH    32768u      // wih B-frags (16x16x32):  2*21*4*64*8*2  = 172032
#define OFF_WHH    204800u     // whh B-frags (16x16x32):  2*21*4*64*8*2  = 172032
#define OFF_BIASP  376832u     // bias (bih + bhh_{r,z}; bih_n): 2*384*4  = 3072
#define OFF_STMT   379904u     // stmt f16 [t*64+b][128]:    4096*128*2   = 1048576

__device__ inline f32x4 zero4() { f32x4 z = {0.f, 0.f, 0.f, 0.f}; return z; }

// minimal-op transcendentals (guaranteed v_exp/v_rcp, no ocml fixup chains)
__device__ inline float fast_exp2(float x) {
  float r; asm("v_exp_f32 %0, %1" : "=v"(r) : "v"(x)); return r;
}
__device__ inline float fast_rcp(float x) {
  float r; asm("v_rcp_f32 %0, %1" : "=v"(r) : "v"(x)); return r;
}
__device__ inline float sigmoid_f(float x) {        // 1/(1+e^-x)
  return fast_rcp(1.f + fast_exp2(x * -1.44269504f));
}
__device__ inline float tanh_f(float x) {           // 1 - 2/(1+e^(2x))
  float e = fast_exp2(x * 2.88539008f);
  return fmaf(fast_rcp(1.f + e), -2.f, 1.f);
}

// K3 LDS swizzle: read 2-way-free AND write conflict-free
#define HSWZ(row) ((((row) & 3) << 4) ^ (((row) & 12) << 3))

// ---------------------------------------------------------------------------
// K1: per-block 4 trees (128 nodes). Blocks 0-86 additionally run the gru
//     weight prep slices. W_lin->frag conversion inline per block (L2-hot).
//     Ancestor walk overlapped into the GEMM1 phase.
//     stmt stored in row' = t*64 + b order (tree g = b*64+t).
// ---------------------------------------------------------------------------
__global__ __launch_bounds__(256, 2) void astnn_tree(
    const int* __restrict__ node_ids, const int* __restrict__ parent,
    const float* __restrict__ emb, const float* __restrict__ W_lin,
    const float* __restrict__ b_lin,
    const float* __restrict__ wihf, const float* __restrict__ whhf,
    const float* __restrict__ bihf, const float* __restrict__ bhhf,
    const float* __restrict__ wihb, const float* __restrict__ whhb,
    const float* __restrict__ bihb, const float* __restrict__ bhhb,
    _Float16* __restrict__ wihfrag, _Float16* __restrict__ whhfrag,
    float* __restrict__ biasP, _Float16* __restrict__ stmt)
{
  __shared__ _Float16 ldsW[16384];   // 32KB: W_lin B-frags (built inline)
  __shared__ _Float16 ldsA[16384];   // 32KB: emb tile (swizzled), reused for h-frags
  __shared__ int ldsPar[128];
  __shared__ unsigned ldsAnc[128];

  const int t = threadIdx.x, blk = blockIdx.x;
  const int w = t >> 6, l = t & 63;
  const int base = blk * 128;

  // ---- gru prep slice (blocks 0-86): wih/whh frags + bias, global-only ----
  if (blk < 87) {
    int gid = blk * 256 + t;                 // 0..22271
    if (gid < 10752) {
      // wih -> 16x16x32 B-frags: N per-section 112 (21 tiles), K=128
      int i = gid, ll = i & 63, kc = (i >> 6) & 3;
      int rest = i >> 8, nt = rest % 21, d = rest / 21;
      const float* wih = d ? wihb : wihf;
      int n = (nt << 4) + (ll & 15), s = n / 112, j = n - 112 * s;
      int kb = (kc << 5) + ((ll >> 4) << 3);
#pragma unroll
      for (int e = 0; e < 8; e++) {
        int k = kb + e;
        float v = (j < HDIM) ? wih[(s * HDIM + j) * CDIM + k] : 0.f;
        wihfrag[i * 8 + e] = (_Float16)v;
      }
    } else if (gid < 21504) {
      // whh -> 16x16x32 B-frags: K padded to 128; k==HDIM (s==2) carries bhh_n
      int i = gid - 10752, ll = i & 63, kc = (i >> 6) & 3;
      int rest = i >> 8, nt = rest % 21, d = rest / 21;
      const float* whh = d ? whhb : whhf;
      const float* bhh = d ? bhhb : bhhf;
      int n = (nt << 4) + (ll & 15), s = n / 112, j = n - 112 * s;
      int kb = (kc << 5) + ((ll >> 4) << 3);
#pragma unroll
      for (int e = 0; e < 8; e++) {
        int k = kb + e;
        float v = 0.f;
        if (j < HDIM) {
          if (k < HDIM) v = whh[(s * HDIM + j) * HDIM + k];
          else if (k == HDIM && s == 2) v = bhh[2 * HDIM + j];
        }
        whhfrag[i * 8 + e] = (_Float16)v;
      }
    } else {
      // biasP[d][384] = bih[g] + (s<2 ? bhh[g] : 0), pad = 0
      int i = gid - 21504, d = i / 384, col = i % 384, s = col >> 7, j = col & 127;
      const float* bih = d ? bihb : bihf;
      const float* bhh = d ? bhhb : bhhf;
      float v = 0.f;
      if (j < HDIM) { v = bih[s * HDIM + j]; if (s < 2) v += bhh[s * HDIM + j]; }
      biasP[i] = v;
    }
  }

  if (t < 128) ldsPar[t] = parent[base + t] & 31;  // trees are 32-aligned globally

  {  // W_lin -> 16x16x32 B-frags directly into ldsW (L2-hot 64KB source)
#pragma unroll
    for (int i8 = 0; i8 < 8; i8++) {
      int fi = i8 * 256 + t;
      int ll = fi & 63, kc = (fi >> 6) & 3, nt = fi >> 8;
      int n = (nt << 4) + (ll & 15);
      int kb = (kc << 5) + ((ll >> 4) << 3);
      H8 u;
#pragma unroll
      for (int e = 0; e < 8; e++)
        u.h[e] = (_Float16)W_lin[(kb + e) * CDIM + n];
      *(float4*)&ldsW[fi * 8] = u.f;
    }
  }

  {  // gather embedding rows -> f16, swizzled row-major [128][128]
    const int r = t >> 1, hf = t & 1;
    const int nid = node_ids[base + r];
    const float4* erow = (const float4*)(emb + (size_t)nid * EDIM) + hf * 16;
#pragma unroll
    for (int b2 = 0; b2 < 2; b2++) {
      float4 stage[8];
#pragma unroll
      for (int i = 0; i < 8; i++) stage[i] = erow[b2 * 8 + i];
#pragma unroll
      for (int c4 = 0; c4 < 4; c4++) {
        H8 u;
#pragma unroll
        for (int e = 0; e < 8; e++)
          u.h[e] = (_Float16)(((const float*)&stage[0])[c4 * 8 + e]);
        int c = b2 * 4 + c4;
        int addr = (r * 256 + hf * 128 + c * 16) ^ ((r & 7) << 4);
        *(float4*)((char*)ldsA + addr) = u.f;
      }
    }
  }
  __syncthreads();   // emb tile + ldsPar ready

  // GEMM: h[128][128] = emb_tile @ W  (16x16x32 f16), wave w owns M-tiles 2w,2w+1
  f32x4 acc[2][8];
#pragma unroll
  for (int mt = 0; mt < 2; mt++)
#pragma unroll
    for (int nt = 0; nt < 8; nt++) acc[mt][nt] = zero4();
#pragma unroll
  for (int kc = 0; kc < 4; kc++) {
    half8 af[2];
#pragma unroll
    for (int mt = 0; mt < 2; mt++) {
      int row = (w * 2 + mt) * 16 + (l & 15);
      int addr = (row * 256 + (kc << 6) + ((l >> 4) << 4)) ^ ((row & 7) << 4);
      af[mt] = *(const half8*)((const char*)ldsA + addr);
    }
#pragma unroll
    for (int nt = 0; nt < 8; nt++) {
      half8 bf = *(const half8*)&ldsW[(((nt << 2) | kc) * 64 + l) * 8];
      acc[0][nt] = __builtin_amdgcn_mfma_f32_16x16x32_f16(af[0], bf, acc[0][nt], 0, 0, 0);
      acc[1][nt] = __builtin_amdgcn_mfma_f32_16x16x32_f16(af[1], bf, acc[1][nt], 0, 0, 0);
    }
  }
  // ancestor walk overlapped with GEMM1 drain (output needed only in GEMM2)
  if (t < 128) {
    int tree = t >> 5;
    unsigned mask = 0;
    int cur = t & 31;
#pragma unroll
    for (int it = 0; it < 11; ++it) { mask |= (1u << cur); cur = ldsPar[tree * 32 + cur]; }
    ldsAnc[t] = mask;
  }
  __syncthreads();  // all emb-tile reads done; ldsA reused for h-fragments

  // write h (+b_lin) into 32x32x16 B-frag layout: [tree][nt2][kc2][lane][8] f16
#pragma unroll
  for (int mt = 0; mt < 2; mt++) {
    const int Mt = w * 2 + mt, tree = Mt >> 1, kc2 = Mt & 1;
#pragma unroll
    for (int nt = 0; nt < 8; nt++) {
      const float bl = b_lin[nt * 16 + (l & 15)];
      const int nt2 = nt >> 1;
      const int ncol = ((nt & 1) << 4) + (l & 15);
#pragma unroll
      for (int reg = 0; reg < 4; reg++) {
        int rowrem = ((l >> 4) << 2) + reg;          // row within 16x16 C tile
        int l2 = ((rowrem >> 3) << 5) + ncol;
        int idx = (((((tree << 2) + nt2) << 1) + kc2) * 64 + l2) * 8 + (rowrem & 7);
        ldsA[idx] = (_Float16)(acc[mt][nt][reg] + bl);
      }
    }
  }
  __syncthreads();

  // per-tree subtree-sum: S[32][128] = anc(0/1) @ h  (32x32x16), wave w = tree w
  {
    const int tree = w;
    half8 ancf[2];
#pragma unroll
    for (int kc2 = 0; kc2 < 2; kc2++) {
      H8 u;
#pragma unroll
      for (int e = 0; e < 8; e++) {
        int n = (kc2 << 4) + ((l >> 5) << 3) + e;
        unsigned m = ldsAnc[(tree << 5) + n];
        u.h[e] = (_Float16)(float)((m >> (l & 31)) & 1u);
      }
      ancf[kc2] = u.h;
    }
    f32x16 acc2[4];
#pragma unroll
    for (int nt2 = 0; nt2 < 4; nt2++)
#pragma unroll
      for (int e = 0; e < 16; e++) acc2[nt2][e] = 0.f;
#pragma unroll
    for (int nt2 = 0; nt2 < 4; nt2++)
#pragma unroll
      for (int kc2 = 0; kc2 < 2; kc2++) {
        half8 bf = *(const half8*)&ldsA[(((((tree << 2) + nt2) << 1) + kc2) * 64 + l) * 8];
        acc2[nt2] = __builtin_amdgcn_mfma_f32_32x32x16_f16(ancf[kc2], bf, acc2[nt2], 0, 0, 0);
      }
    // max-pool over the 32 node rows -> stmt[row'][c], row' = t*64 + b
#pragma unroll
    for (int nt2 = 0; nt2 < 4; nt2++) {
      float m1 = acc2[nt2][0];
#pragma unroll
      for (int e = 1; e < 16; e++) m1 = fmaxf(m1, acc2[nt2][e]);
      m1 = fmaxf(m1, __shfl_xor(m1, 32));
      if (l < 32) {
        int g = blk * 4 + tree;                      // tree = b*64 + t
        int rowp = (g & 63) * 64 + (g >> 6);         // row' = t*64 + b
        stmt[(size_t)rowp * CDIM + (nt2 << 5) + l] = (_Float16)m1;
      }
    }
  }
}

// ---------------------------------------------------------------------------
// K3: bidirectional GRU with fused input GEMM (pipelined 1 step ahead) AND
//     fused FC epilogue. Loop body = r10 form: whh chain accumulates into
//     FRESH acc registers copied from the consumed gi set (the r11 in-place
//     variant serialized the matrix pipe across steps: 52.5 -> 75.4 us).
//     After 64 steps each block writes pool to LDS, computes its 16x104
//     partial out = pool @ fc_w[dir] (+fc_b on dir0), atomicAdds into out
//     (out zeroed via hipMemsetAsync at call start).
//     Grid (4 mb, 2 dirs), 7 waves; wave w owns cols j=16w+(l&15).
//     bhh_n via constant h col 100 = 1.0 + whh k=100 carrier.
// ---------------------------------------------------------------------------
__global__ __launch_bounds__(448) void astnn_gru(
    const _Float16* __restrict__ whhfrag, const _Float16* __restrict__ wihfrag,
    const _Float16* __restrict__ stmt, const float* __restrict__ biasP,
    const float* __restrict__ fc_w, const float* __restrict__ fc_b,
    float* __restrict__ out)
{
  __shared__ _Float16 hlds[4096];  // 2 x (16 rows x 128 cols f16, swizzled)
  const int t = threadIdx.x, w = t >> 6, l = t & 63;
  const int mb = blockIdx.x, dir = blockIdx.y;
  for (int i = t; i < 512; i += 448)          // zero BOTH buffers
    ((float4*)hlds)[i] = make_float4(0.f, 0.f, 0.f, 0.f);
  __syncthreads();
  if (t < 32) {                               // h col 100 = 1.0 (bhh_n carrier)
    int row = t & 15, buf = t >> 4;
    int addr = ((row * 256 + 200) ^ HSWZ(row)) + (buf << 12);
    *(_Float16*)((char*)hlds + addr) = (_Float16)1.0f;
  }

  const int j = (w << 4) + (l & 15);
  const bool jv = (j < HDIM);
  const int rloc = (l >> 4) << 2;             // local row base: 0,4,8,12

  // hoisted LDS addresses (swizzle HSWZ)
  int raddr[4], waddr[4];
  {
    int row = l & 15;
#pragma unroll
    for (int kc = 0; kc < 4; kc++)
      raddr[kc] = (row * 256 + (kc << 6) + ((l >> 4) << 4)) ^ HSWZ(row);
#pragma unroll
    for (int reg = 0; reg < 4; reg++) {
      int rw = rloc + reg;
      waddr[reg] = (rw * 256 + (j << 1)) ^ HSWZ(rw);
    }
  }

  // weight B-frags: whh (hidden) and wih (input), same frag geometry
  half8 bfr[3][4], bfw[3][4];
  {
    const half8* wfh = (const half8*)whhfrag + dir * 5376;
    const half8* wfi = (const half8*)wihfrag + dir * 5376;
#pragma unroll
    for (int s = 0; s < 3; s++)
#pragma unroll
      for (int kc = 0; kc < 4; kc++) {
        int idx = (((s * 7 + w) << 2) + kc) * 64 + l;
        bfr[s][kc] = wfh[idx];
        bfw[s][kc] = wfi[idx];
      }
  }
  const float bias0 = biasP[dir * 384 + j];
  const float bias1 = biasP[dir * 384 + 128 + j];
  const float bias2 = biasP[dir * 384 + 256 + j];

  // stmt slab loads: lane-fixed byte offsets + SALU-stepped t pointer
  int soff[4];
#pragma unroll
  for (int kc = 0; kc < 4; kc++)
    soff[kc] = (((mb << 4) + (l & 15)) * 256) + (kc << 6) + ((l >> 4) << 4);
  const ptrdiff_t sstep = dir ? -16384 : 16384;   // 64 rows * 256B per t
  const char* sbase = (const char*)stmt + (size_t)(dir ? 63 : 0) * 16384;

  half8 sfA[4], sfB[4];
#pragma unroll
  for (int kc = 0; kc < 4; kc++) sfA[kc] = *(const half8*)(sbase + soff[kc]);
  const char* spre = sbase + sstep;
#pragma unroll
  for (int kc = 0; kc < 4; kc++) sfB[kc] = *(const half8*)(spre + soff[kc]);
  spre += sstep;

  // prologue: giA = bias + wih @ stmt[t0]
  f32x4 giA[3], giB[3];
  giA[0] = f32x4{bias0, bias0, bias0, bias0};
  giA[1] = f32x4{bias1, bias1, bias1, bias1};
  giA[2] = f32x4{bias2, bias2, bias2, bias2};
#pragma unroll
  for (int kc = 0; kc < 4; kc++) {
    giA[0] = __builtin_amdgcn_mfma_f32_16x16x32_f16(sfA[kc], bfw[0][kc], giA[0], 0, 0, 0);
    giA[1] = __builtin_amdgcn_mfma_f32_16x16x32_f16(sfA[kc], bfw[1][kc], giA[1], 0, 0, 0);
    giA[2] = __builtin_amdgcn_mfma_f32_16x16x32_f16(sfA[kc], bfw[2][kc], giA[2], 0, 0, 0);
  }

  float hreg[4], pool[4];
#pragma unroll
  for (int i = 0; i < 4; i++) { hreg[i] = 0.f; pool[i] = -3.0e38f; }
  __syncthreads();

  // GIC: gi consumed this step (copied into fresh accs — NOT in-place).
  // GIN: gi computed for next step from SFsrc. SFdst: prefetch target.
#define GRU_BODY(GIC, GIN, SFsrc, SFdst, ROFF, WOFF, CN, PF)                    \
  {                                                                             \
    half8 afh[4];                                                               \
    _Pragma("unroll")                                                           \
    for (int kc = 0; kc < 4; kc++)                                              \
      afh[kc] = *(const half8*)((const char*)hlds + raddr[kc] + (ROFF));        \
    f32x4 acc0 = GIC[0], acc1 = GIC[1];                                         \
    f32x4 acc2i = GIC[2], acc2h = zero4();                                      \
    _Pragma("unroll")  /* critical whh chain FIRST */                           \
    for (int kc = 0; kc < 4; kc++) {                                            \
      acc0  = __builtin_amdgcn_mfma_f32_16x16x32_f16(afh[kc], bfr[0][kc], acc0, 0, 0, 0); \
      acc1  = __builtin_amdgcn_mfma_f32_16x16x32_f16(afh[kc], bfr[1][kc], acc1, 0, 0, 0); \
      acc2h = __builtin_amdgcn_mfma_f32_16x16x32_f16(afh[kc], bfr[2][kc], acc2h, 0, 0, 0);\
    }                                                                           \
    if (CN) {  /* independent next-step gi chain: fills whh->gates latency */   \
      GIN[0] = f32x4{bias0, bias0, bias0, bias0};                               \
      GIN[1] = f32x4{bias1, bias1, bias1, bias1};                               \
      GIN[2] = f32x4{bias2, bias2, bias2, bias2};                               \
      _Pragma("unroll")                                                         \
      for (int kc = 0; kc < 4; kc++) {                                          \
        GIN[0] = __builtin_amdgcn_mfma_f32_16x16x32_f16(SFsrc[kc], bfw[0][kc], GIN[0], 0, 0, 0); \
        GIN[1] = __builtin_amdgcn_mfma_f32_16x16x32_f16(SFsrc[kc], bfw[1][kc], GIN[1], 0, 0, 0); \
        GIN[2] = __builtin_amdgcn_mfma_f32_16x16x32_f16(SFsrc[kc], bfw[2][kc], GIN[2], 0, 0, 0); \
      }                                                                         \
    }                                                                           \
    if (PF) {                                                                   \
      SFdst[0] = *(const half8*)(spre + soff[0]);                               \
      SFdst[1] = *(const half8*)(spre + soff[1]);                               \
      SFdst[2] = *(const half8*)(spre + soff[2]);                               \
      SFdst[3] = *(const half8*)(spre + soff[3]);                               \
      spre += sstep;                                                            \
    }                                                                           \
    _Pragma("unroll")                                                           \
    for (int reg = 0; reg < 4; reg++) {                                         \
      float r = sigmoid_f(acc0[reg]);                                           \
      float z = sigmoid_f(acc1[reg]);                                           \
      float n = tanh_f(fmaf(r, acc2h[reg], acc2i[reg]));                        \
      float hn = n + z * (hreg[reg] - n);                                       \
      hreg[reg] = hn;                                                           \
      pool[reg] = fmaxf(pool[reg], hn);                                         \
      if (jv)                                                                   \
        *(_Float16*)((char*)hlds + waddr[reg] + (WOFF)) = (_Float16)hn;         \
    }                                                                           \
    asm volatile("s_waitcnt lgkmcnt(0)" ::: "memory");                          \
    __builtin_amdgcn_s_barrier();                                               \
    __builtin_amdgcn_sched_barrier(0);                                          \
  }

#pragma unroll 1
  for (int it = 0; it < 31; ++it) {
    GRU_BODY(giA, giB, sfB, sfA, 0, 4096, 1, 1)       // even step 2it
    GRU_BODY(giB, giA, sfA, sfB, 4096, 0, 1, 1)       // odd  step 2it+1
  }
  GRU_BODY(giA, giB, sfB, sfA, 0, 4096, 1, 0)         // step 62
  GRU_BODY(giB, giA, sfA, sfB, 4096, 0, 0, 0)         // step 63
#undef GRU_BODY

  // ---- fused FC epilogue: partial out[16 x 104] from this block's pool ----
  float* pl = (float*)hlds;                   // [112 cols][16 rows] f32 = 7168B
  if (jv) {
    float4 v = make_float4(pool[0], pool[1], pool[2], pool[3]);
    *(float4*)(pl + j * 16 + rloc) = v;       // rows rloc..rloc+3, col j
  }
  __syncthreads();
  {
    const float* fcw = fc_w + (size_t)dir * HDIM * ODIM;
    for (int i = t; i < 16 * ODIM; i += 448) {
      int row = i / ODIM, o = i - row * ODIM;
      float s = dir ? 0.f : fc_b[o];
#pragma unroll 4
      for (int k = 0; k < HDIM; k++)
        s = fmaf(pl[k * 16 + row], fcw[k * ODIM + o], s);
      atomicAdd(&out[(size_t)((mb << 4) + row) * ODIM + o], s);
    }
  }
}

// ---------------------------------------------------------------------------
extern "C" void kernel_launch(void* const* d_in, const int* in_sizes, int n_in,
                              void* d_out, int out_size, void* d_ws, size_t ws_size,
                              hipStream_t stream)
{
  const int* node_ids = (const int*)d_in[0];
  const int* parent   = (const int*)d_in[1];
  // d_in[2]=level, d_in[3]=tree_id: unused (decreasing-index order suffices)
  const float* emb    = (const float*)d_in[4];
  const float* W_lin  = (const float*)d_in[5];
  const float* b_lin  = (const float*)d_in[6];
  const float* wihf   = (const float*)d_in[7];
  const float* whhf   = (const float*)d_in[8];
  const float* bihf   = (const float*)d_in[9];
  const float* bhhf   = (const float*)d_in[10];
  const float* wihb   = (const float*)d_in[11];
  const float* whhb   = (const float*)d_in[12];
  const float* bihb   = (const float*)d_in[13];
  const float* bhhb   = (const float*)d_in[14];
  const float* fc_w   = (const float*)d_in[15];
  const float* fc_b   = (const float*)d_in[16];

  char* ws = (char*)d_ws;
  _Float16* wihfrag = (_Float16*)(ws + OFF_WIH);
  _Float16* whhfrag = (_Float16*)(ws + OFF_WHH);
  float* biasP      = (float*)(ws + OFF_BIASP);
  _Float16* stmt    = (_Float16*)(ws + OFF_STMT);
  float* out        = (float*)d_out;

  hipMemsetAsync(d_out, 0, (size_t)out_size * sizeof(float), stream);
  astnn_tree<<<1024, 256, 0, stream>>>(node_ids, parent, emb, W_lin, b_lin,
                                       wihf, whhf, bihf, bhhf,
                                       wihb, whhb, bihb, bhhb,
                                       wihfrag, whhfrag, biasP, stmt);
  astnn_gru<<<dim3(4, 2), 448, 0, stream>>>(whhfrag, wihfrag, stmt, biasP,
                                            fc_w, fc_b, out);
}

// Round 13
// 85.671 us; speedup vs baseline: 1.1741x; 1.1724x over previous
//
#include <hip/hip_runtime.h>

typedef _Float16 half8 __attribute__((ext_vector_type(8)));
typedef float f32x4 __attribute__((ext_vector_type(4)));
typedef float f32x16 __attribute__((ext_vector_type(16)));

union H8 { half8 h; float4 f; };

#define EDIM 128
#define CDIM 128
#define HDIM 100
#define ODIM 104

// workspace offsets (bytes), 256-aligned
#define OFF_WIH    32768u      // wih B-frags (16x16x32):  2*21*4*64*8*2  = 172032
#define OFF_WHH    204800u     // whh B-frags (16x16x32):  2*21*4*64*8*2  = 172032
#define OFF_BIASP  376832u     // bias (bih + bhh_{r,z}; bih_n): 2*384*4  = 3072
#define OFF_STMT   379904u     // stmt f16 [t*64+b][128]:    4096*128*2   = 1048576
#define OFF_POOL   1428480u    // pooled fp32: 2*64*128*4                 = 65536

__device__ inline f32x4 zero4() { f32x4 z = {0.f, 0.f, 0.f, 0.f}; return z; }

// minimal-op transcendentals (guaranteed v_exp/v_rcp, no ocml fixup chains)
__device__ inline float fast_exp2(float x) {
  float r; asm("v_exp_f32 %0, %1" : "=v"(r) : "v"(x)); return r;
}
__device__ inline float fast_rcp(float x) {
  float r; asm("v_rcp_f32 %0, %1" : "=v"(r) : "v"(x)); return r;
}
__device__ inline float sigmoid_f(float x) {        // 1/(1+e^-x)
  return fast_rcp(1.f + fast_exp2(x * -1.44269504f));
}
__device__ inline float tanh_f(float x) {           // 1 - 2/(1+e^(2x))
  float e = fast_exp2(x * 2.88539008f);
  return fmaf(fast_rcp(1.f + e), -2.f, 1.f);
}

// K3 LDS swizzle: read 2-way-free AND write conflict-free
#define HSWZ(row) ((((row) & 3) << 4) ^ (((row) & 12) << 3))

// ---------------------------------------------------------------------------
// K1: per-block 4 trees (128 nodes). Blocks 0-86 additionally run the gru
//     weight prep slices. W_lin->frag conversion inline per block (L2-hot).
//     Ancestor walk overlapped into the GEMM1 phase.
//     stmt stored in row' = t*64 + b order (tree g = b*64+t).
// ---------------------------------------------------------------------------
__global__ __launch_bounds__(256, 2) void astnn_tree(
    const int* __restrict__ node_ids, const int* __restrict__ parent,
    const float* __restrict__ emb, const float* __restrict__ W_lin,
    const float* __restrict__ b_lin,
    const float* __restrict__ wihf, const float* __restrict__ whhf,
    const float* __restrict__ bihf, const float* __restrict__ bhhf,
    const float* __restrict__ wihb, const float* __restrict__ whhb,
    const float* __restrict__ bihb, const float* __restrict__ bhhb,
    _Float16* __restrict__ wihfrag, _Float16* __restrict__ whhfrag,
    float* __restrict__ biasP, _Float16* __restrict__ stmt)
{
  __shared__ _Float16 ldsW[16384];   // 32KB: W_lin B-frags (built inline)
  __shared__ _Float16 ldsA[16384];   // 32KB: emb tile (swizzled), reused for h-frags
  __shared__ int ldsPar[128];
  __shared__ unsigned ldsAnc[128];

  const int t = threadIdx.x, blk = blockIdx.x;
  const int w = t >> 6, l = t & 63;
  const int base = blk * 128;

  // ---- gru prep slice (blocks 0-86): wih/whh frags + bias, global-only ----
  if (blk < 87) {
    int gid = blk * 256 + t;                 // 0..22271
    if (gid < 10752) {
      // wih -> 16x16x32 B-frags: N per-section 112 (21 tiles), K=128
      int i = gid, ll = i & 63, kc = (i >> 6) & 3;
      int rest = i >> 8, nt = rest % 21, d = rest / 21;
      const float* wih = d ? wihb : wihf;
      int n = (nt << 4) + (ll & 15), s = n / 112, j = n - 112 * s;
      int kb = (kc << 5) + ((ll >> 4) << 3);
#pragma unroll
      for (int e = 0; e < 8; e++) {
        int k = kb + e;
        float v = (j < HDIM) ? wih[(s * HDIM + j) * CDIM + k] : 0.f;
        wihfrag[i * 8 + e] = (_Float16)v;
      }
    } else if (gid < 21504) {
      // whh -> 16x16x32 B-frags: K padded to 128; k==HDIM (s==2) carries bhh_n
      int i = gid - 10752, ll = i & 63, kc = (i >> 6) & 3;
      int rest = i >> 8, nt = rest % 21, d = rest / 21;
      const float* whh = d ? whhb : whhf;
      const float* bhh = d ? bhhb : bhhf;
      int n = (nt << 4) + (ll & 15), s = n / 112, j = n - 112 * s;
      int kb = (kc << 5) + ((ll >> 4) << 3);
#pragma unroll
      for (int e = 0; e < 8; e++) {
        int k = kb + e;
        float v = 0.f;
        if (j < HDIM) {
          if (k < HDIM) v = whh[(s * HDIM + j) * HDIM + k];
          else if (k == HDIM && s == 2) v = bhh[2 * HDIM + j];
        }
        whhfrag[i * 8 + e] = (_Float16)v;
      }
    } else {
      // biasP[d][384] = bih[g] + (s<2 ? bhh[g] : 0), pad = 0
      int i = gid - 21504, d = i / 384, col = i % 384, s = col >> 7, j = col & 127;
      const float* bih = d ? bihb : bihf;
      const float* bhh = d ? bhhb : bhhf;
      float v = 0.f;
      if (j < HDIM) { v = bih[s * HDIM + j]; if (s < 2) v += bhh[s * HDIM + j]; }
      biasP[i] = v;
    }
  }

  if (t < 128) ldsPar[t] = parent[base + t] & 31;  // trees are 32-aligned globally

  {  // W_lin -> 16x16x32 B-frags directly into ldsW (L2-hot 64KB source)
#pragma unroll
    for (int i8 = 0; i8 < 8; i8++) {
      int fi = i8 * 256 + t;
      int ll = fi & 63, kc = (fi >> 6) & 3, nt = fi >> 8;
      int n = (nt << 4) + (ll & 15);
      int kb = (kc << 5) + ((ll >> 4) << 3);
      H8 u;
#pragma unroll
      for (int e = 0; e < 8; e++)
        u.h[e] = (_Float16)W_lin[(kb + e) * CDIM + n];
      *(float4*)&ldsW[fi * 8] = u.f;
    }
  }

  {  // gather embedding rows -> f16, swizzled row-major [128][128]
    const int r = t >> 1, hf = t & 1;
    const int nid = node_ids[base + r];
    const float4* erow = (const float4*)(emb + (size_t)nid * EDIM) + hf * 16;
#pragma unroll
    for (int b2 = 0; b2 < 2; b2++) {
      float4 stage[8];
#pragma unroll
      for (int i = 0; i < 8; i++) stage[i] = erow[b2 * 8 + i];
#pragma unroll
      for (int c4 = 0; c4 < 4; c4++) {
        H8 u;
#pragma unroll
        for (int e = 0; e < 8; e++)
          u.h[e] = (_Float16)(((const float*)&stage[0])[c4 * 8 + e]);
        int c = b2 * 4 + c4;
        int addr = (r * 256 + hf * 128 + c * 16) ^ ((r & 7) << 4);
        *(float4*)((char*)ldsA + addr) = u.f;
      }
    }
  }
  __syncthreads();   // emb tile + ldsPar ready

  // GEMM: h[128][128] = emb_tile @ W  (16x16x32 f16), wave w owns M-tiles 2w,2w+1
  f32x4 acc[2][8];
#pragma unroll
  for (int mt = 0; mt < 2; mt++)
#pragma unroll
    for (int nt = 0; nt < 8; nt++) acc[mt][nt] = zero4();
#pragma unroll
  for (int kc = 0; kc < 4; kc++) {
    half8 af[2];
#pragma unroll
    for (int mt = 0; mt < 2; mt++) {
      int row = (w * 2 + mt) * 16 + (l & 15);
      int addr = (row * 256 + (kc << 6) + ((l >> 4) << 4)) ^ ((row & 7) << 4);
      af[mt] = *(const half8*)((const char*)ldsA + addr);
    }
#pragma unroll
    for (int nt = 0; nt < 8; nt++) {
      half8 bf = *(const half8*)&ldsW[(((nt << 2) | kc) * 64 + l) * 8];
      acc[0][nt] = __builtin_amdgcn_mfma_f32_16x16x32_f16(af[0], bf, acc[0][nt], 0, 0, 0);
      acc[1][nt] = __builtin_amdgcn_mfma_f32_16x16x32_f16(af[1], bf, acc[1][nt], 0, 0, 0);
    }
  }
  // ancestor walk overlapped with GEMM1 drain (output needed only in GEMM2)
  if (t < 128) {
    int tree = t >> 5;
    unsigned mask = 0;
    int cur = t & 31;
#pragma unroll
    for (int it = 0; it < 11; ++it) { mask |= (1u << cur); cur = ldsPar[tree * 32 + cur]; }
    ldsAnc[t] = mask;
  }
  __syncthreads();  // all emb-tile reads done; ldsA reused for h-fragments

  // write h (+b_lin) into 32x32x16 B-frag layout: [tree][nt2][kc2][lane][8] f16
#pragma unroll
  for (int mt = 0; mt < 2; mt++) {
    const int Mt = w * 2 + mt, tree = Mt >> 1, kc2 = Mt & 1;
#pragma unroll
    for (int nt = 0; nt < 8; nt++) {
      const float bl = b_lin[nt * 16 + (l & 15)];
      const int nt2 = nt >> 1;
      const int ncol = ((nt & 1) << 4) + (l & 15);
#pragma unroll
      for (int reg = 0; reg < 4; reg++) {
        int rowrem = ((l >> 4) << 2) + reg;          // row within 16x16 C tile
        int l2 = ((rowrem >> 3) << 5) + ncol;
        int idx = (((((tree << 2) + nt2) << 1) + kc2) * 64 + l2) * 8 + (rowrem & 7);
        ldsA[idx] = (_Float16)(acc[mt][nt][reg] + bl);
      }
    }
  }
  __syncthreads();

  // per-tree subtree-sum: S[32][128] = anc(0/1) @ h  (32x32x16), wave w = tree w
  {
    const int tree = w;
    half8 ancf[2];
#pragma unroll
    for (int kc2 = 0; kc2 < 2; kc2++) {
      H8 u;
#pragma unroll
      for (int e = 0; e < 8; e++) {
        int n = (kc2 << 4) + ((l >> 5) << 3) + e;
        unsigned m = ldsAnc[(tree << 5) + n];
        u.h[e] = (_Float16)(float)((m >> (l & 31)) & 1u);
      }
      ancf[kc2] = u.h;
    }
    f32x16 acc2[4];
#pragma unroll
    for (int nt2 = 0; nt2 < 4; nt2++)
#pragma unroll
      for (int e = 0; e < 16; e++) acc2[nt2][e] = 0.f;
#pragma unroll
    for (int nt2 = 0; nt2 < 4; nt2++)
#pragma unroll
      for (int kc2 = 0; kc2 < 2; kc2++) {
        half8 bf = *(const half8*)&ldsA[(((((tree << 2) + nt2) << 1) + kc2) * 64 + l) * 8];
        acc2[nt2] = __builtin_amdgcn_mfma_f32_32x32x16_f16(ancf[kc2], bf, acc2[nt2], 0, 0, 0);
      }
    // max-pool over the 32 node rows -> stmt[row'][c], row' = t*64 + b
#pragma unroll
    for (int nt2 = 0; nt2 < 4; nt2++) {
      float m1 = acc2[nt2][0];
#pragma unroll
      for (int e = 1; e < 16; e++) m1 = fmaxf(m1, acc2[nt2][e]);
      m1 = fmaxf(m1, __shfl_xor(m1, 32));
      if (l < 32) {
        int g = blk * 4 + tree;                      // tree = b*64 + t
        int rowp = (g & 63) * 64 + (g >> 6);         // row' = t*64 + b
        stmt[(size_t)rowp * CDIM + (nt2 << 5) + l] = (_Float16)m1;
      }
    }
  }
}

// ---------------------------------------------------------------------------
// K3: bidirectional GRU with fused input GEMM, software-pipelined one step.
//     EXACT r10 form (pooled-store epilogue; no FC fusion — the r11 fused-FC
//     epilogue degraded the loop's codegen: 52.5 -> 75.4 us with an
//     identical loop body). Grid (4 mb, 2 dirs), 7 waves.
//     bhh_n via constant h col 100 = 1.0 + whh k=100 carrier.
// ---------------------------------------------------------------------------
__global__ __launch_bounds__(448) void astnn_gru(
    const _Float16* __restrict__ whhfrag, const _Float16* __restrict__ wihfrag,
    const _Float16* __restrict__ stmt, const float* __restrict__ biasP,
    float* __restrict__ pooled)
{
  __shared__ _Float16 hlds[4096];  // 2 x (16 rows x 128 cols f16, swizzled)
  const int t = threadIdx.x, w = t >> 6, l = t & 63;
  const int mb = blockIdx.x, dir = blockIdx.y;
  for (int i = t; i < 512; i += 448)          // zero BOTH buffers
    ((float4*)hlds)[i] = make_float4(0.f, 0.f, 0.f, 0.f);
  __syncthreads();
  if (t < 32) {                               // h col 100 = 1.0 (bhh_n carrier)
    int row = t & 15, buf = t >> 4;
    int addr = ((row * 256 + 200) ^ HSWZ(row)) + (buf << 12);
    *(_Float16*)((char*)hlds + addr) = (_Float16)1.0f;
  }

  const int j = (w << 4) + (l & 15);
  const bool jv = (j < HDIM);
  const int rloc = (l >> 4) << 2;             // local row base: 0,4,8,12
  const int grow = (mb << 4) + rloc;          // global batch row base

  // hoisted LDS addresses (swizzle HSWZ)
  int raddr[4], waddr[4];
  {
    int row = l & 15;
#pragma unroll
    for (int kc = 0; kc < 4; kc++)
      raddr[kc] = (row * 256 + (kc << 6) + ((l >> 4) << 4)) ^ HSWZ(row);
#pragma unroll
    for (int reg = 0; reg < 4; reg++) {
      int rw = rloc + reg;
      waddr[reg] = (rw * 256 + (j << 1)) ^ HSWZ(rw);
    }
  }

  // weight B-frags: whh (hidden) and wih (input), same frag geometry
  half8 bfr[3][4], bfw[3][4];
  {
    const half8* wfh = (const half8*)whhfrag + dir * 5376;
    const half8* wfi = (const half8*)wihfrag + dir * 5376;
#pragma unroll
    for (int s = 0; s < 3; s++)
#pragma unroll
      for (int kc = 0; kc < 4; kc++) {
        int idx = (((s * 7 + w) << 2) + kc) * 64 + l;
        bfr[s][kc] = wfh[idx];
        bfw[s][kc] = wfi[idx];
      }
  }
  const float bias0 = biasP[dir * 384 + j];
  const float bias1 = biasP[dir * 384 + 128 + j];
  const float bias2 = biasP[dir * 384 + 256 + j];

  // stmt slab loads: lane-fixed byte offsets + SALU-stepped t pointer
  int soff[4];
#pragma unroll
  for (int kc = 0; kc < 4; kc++)
    soff[kc] = (((mb << 4) + (l & 15)) * 256) + (kc << 6) + ((l >> 4) << 4);
  const ptrdiff_t sstep = dir ? -16384 : 16384;   // 64 rows * 256B per t
  const char* sbase = (const char*)stmt + (size_t)(dir ? 63 : 0) * 16384;

  half8 sfA[4], sfB[4];
#pragma unroll
  for (int kc = 0; kc < 4; kc++) sfA[kc] = *(const half8*)(sbase + soff[kc]);
  const char* spre = sbase + sstep;
#pragma unroll
  for (int kc = 0; kc < 4; kc++) sfB[kc] = *(const half8*)(spre + soff[kc]);
  spre += sstep;

  // prologue: giA = bias + wih @ stmt[t0]
  f32x4 giA[3], giB[3];
  giA[0] = f32x4{bias0, bias0, bias0, bias0};
  giA[1] = f32x4{bias1, bias1, bias1, bias1};
  giA[2] = f32x4{bias2, bias2, bias2, bias2};
#pragma unroll
  for (int kc = 0; kc < 4; kc++) {
    giA[0] = __builtin_amdgcn_mfma_f32_16x16x32_f16(sfA[kc], bfw[0][kc], giA[0], 0, 0, 0);
    giA[1] = __builtin_amdgcn_mfma_f32_16x16x32_f16(sfA[kc], bfw[1][kc], giA[1], 0, 0, 0);
    giA[2] = __builtin_amdgcn_mfma_f32_16x16x32_f16(sfA[kc], bfw[2][kc], giA[2], 0, 0, 0);
  }

  float hreg[4], pool[4];
#pragma unroll
  for (int i = 0; i < 4; i++) { hreg[i] = 0.f; pool[i] = -3.0e38f; }
  __syncthreads();

  // GIC: gi consumed this step (copied into fresh accs — NOT in-place).
  // GIN: gi computed for next step from SFsrc. SFdst: prefetch target.
#define GRU_BODY(GIC, GIN, SFsrc, SFdst, ROFF, WOFF, CN, PF)                    \
  {                                                                             \
    half8 afh[4];                                                               \
    _Pragma("unroll")                                                           \
    for (int kc = 0; kc < 4; kc++)                                              \
      afh[kc] = *(const half8*)((const char*)hlds + raddr[kc] + (ROFF));        \
    f32x4 acc0 = GIC[0], acc1 = GIC[1];                                         \
    f32x4 acc2i = GIC[2], acc2h = zero4();                                      \
    _Pragma("unroll")  /* critical whh chain FIRST */                           \
    for (int kc = 0; kc < 4; kc++) {                                            \
      acc0  = __builtin_amdgcn_mfma_f32_16x16x32_f16(afh[kc], bfr[0][kc], acc0, 0, 0, 0); \
      acc1  = __builtin_amdgcn_mfma_f32_16x16x32_f16(afh[kc], bfr[1][kc], acc1, 0, 0, 0); \
      acc2h = __builtin_amdgcn_mfma_f32_16x16x32_f16(afh[kc], bfr[2][kc], acc2h, 0, 0, 0);\
    }                                                                           \
    if (CN) {  /* independent next-step gi chain: fills whh->gates latency */   \
      GIN[0] = f32x4{bias0, bias0, bias0, bias0};                               \
      GIN[1] = f32x4{bias1, bias1, bias1, bias1};                               \
      GIN[2] = f32x4{bias2, bias2, bias2, bias2};                               \
      _Pragma("unroll")                                                         \
      for (int kc = 0; kc < 4; kc++) {                                          \
        GIN[0] = __builtin_amdgcn_mfma_f32_16x16x32_f16(SFsrc[kc], bfw[0][kc], GIN[0], 0, 0, 0); \
        GIN[1] = __builtin_amdgcn_mfma_f32_16x16x32_f16(SFsrc[kc], bfw[1][kc], GIN[1], 0, 0, 0); \
        GIN[2] = __builtin_amdgcn_mfma_f32_16x16x32_f16(SFsrc[kc], bfw[2][kc], GIN[2], 0, 0, 0); \
      }                                                                         \
    }                                                                           \
    if (PF) {                                                                   \
      SFdst[0] = *(const half8*)(spre + soff[0]);                               \
      SFdst[1] = *(const half8*)(spre + soff[1]);                               \
      SFdst[2] = *(const half8*)(spre + soff[2]);                               \
      SFdst[3] = *(const half8*)(spre + soff[3]);                               \
      spre += sstep;                                                            \
    }                                                                           \
    _Pragma("unroll")                                                           \
    for (int reg = 0; reg < 4; reg++) {                                         \
      float r = sigmoid_f(acc0[reg]);                                           \
      float z = sigmoid_f(acc1[reg]);                                           \
      float n = tanh_f(fmaf(r, acc2h[reg], acc2i[reg]));                        \
      float hn = n + z * (hreg[reg] - n);                                       \
      hreg[reg] = hn;                                                           \
      pool[reg] = fmaxf(pool[reg], hn);                                         \
      if (jv)                                                                   \
        *(_Float16*)((char*)hlds + waddr[reg] + (WOFF)) = (_Float16)hn;         \
    }                                                                           \
    asm volatile("s_waitcnt lgkmcnt(0)" ::: "memory");                          \
    __builtin_amdgcn_s_barrier();                                               \
    __builtin_amdgcn_sched_barrier(0);                                          \
  }

#pragma unroll 1
  for (int it = 0; it < 31; ++it) {
    GRU_BODY(giA, giB, sfB, sfA, 0, 4096, 1, 1)       // even step 2it
    GRU_BODY(giB, giA, sfA, sfB, 4096, 0, 1, 1)       // odd  step 2it+1
  }
  GRU_BODY(giA, giB, sfB, sfA, 0, 4096, 1, 0)         // step 62
  GRU_BODY(giB, giA, sfA, sfB, 4096, 0, 0, 0)         // step 63
#undef GRU_BODY

  if (jv) {
#pragma unroll
    for (int reg = 0; reg < 4; reg++)
      pooled[((size_t)dir << 13) + ((size_t)(grow + reg) << 7) + j] = pool[reg];
  }
}

// ---------------------------------------------------------------------------
// K4: out[b][o] = [pooled_f | pooled_b] @ fc_w + fc_b
// ---------------------------------------------------------------------------
__global__ __launch_bounds__(128) void astnn_fc(
    const float* __restrict__ pooled, const float* __restrict__ fc_w,
    const float* __restrict__ fc_b, float* __restrict__ out)
{
  __shared__ float p[200];
  const int b = blockIdx.x, t = threadIdx.x;
  for (int i = t; i < 200; i += 128) {
    int d = i / 100, jj = i - d * 100;
    p[i] = pooled[((size_t)d << 13) + (b << 7) + jj];
  }
  __syncthreads();
  if (t < ODIM) {
    float a = fc_b[t];
#pragma unroll 8
    for (int k = 0; k < 200; k++) a = fmaf(p[k], fc_w[k * ODIM + t], a);
    out[b * ODIM + t] = a;
  }
}

// ---------------------------------------------------------------------------
extern "C" void kernel_launch(void* const* d_in, const int* in_sizes, int n_in,
                              void* d_out, int out_size, void* d_ws, size_t ws_size,
                              hipStream_t stream)
{
  const int* node_ids = (const int*)d_in[0];
  const int* parent   = (const int*)d_in[1];
  // d_in[2]=level, d_in[3]=tree_id: unused (decreasing-index order suffices)
  const float* emb    = (const float*)d_in[4];
  const float* W_lin  = (const float*)d_in[5];
  const float* b_lin  = (const float*)d_in[6];
  const float* wihf   = (const float*)d_in[7];
  const float* whhf   = (const float*)d_in[8];
  const float* bihf   = (const float*)d_in[9];
  const float* bhhf   = (const float*)d_in[10];
  const float* wihb   = (const float*)d_in[11];
  const float* whhb   = (const float*)d_in[12];
  const float* bihb   = (const float*)d_in[13];
  const float* bhhb   = (const float*)d_in[14];
  const float* fc_w   = (const float*)d_in[15];
  const float* fc_b   = (const float*)d_in[16];

  char* ws = (char*)d_ws;
  _Float16* wihfrag = (_Float16*)(ws + OFF_WIH);
  _Float16* whhfrag = (_Float16*)(ws + OFF_WHH);
  float* biasP      = (float*)(ws + OFF_BIASP);
  _Float16* stmt    = (_Float16*)(ws + OFF_STMT);
  float* pooled     = (float*)(ws + OFF_POOL);
  float* out        = (float*)d_out;

  astnn_tree<<<1024, 256, 0, stream>>>(node_ids, parent, emb, W_lin, b_lin,
                                       wihf, whhf, bihf, bhhf,
                                       wihb, whhb, bihb, bhhb,
                                       wihfrag, whhfrag, biasP, stmt);
  astnn_gru<<<dim3(4, 2), 448, 0, stream>>>(whhfrag, wihfrag, stmt, biasP, pooled);
  astnn_fc<<<64, 128, 0, stream>>>(pooled, fc_w, fc_b, out);
}

// Round 14
// 83.330 us; speedup vs baseline: 1.2071x; 1.0281x over previous
//
#include <hip/hip_runtime.h>

typedef _Float16 half8 __attribute__((ext_vector_type(8)));
typedef _Float16 half4v __attribute__((ext_vector_type(4)));
typedef float f32x4 __attribute__((ext_vector_type(4)));
typedef float f32x16 __attribute__((ext_vector_type(16)));

union H8 { half8 h; float4 f; };

#define EDIM 128
#define CDIM 128
#define HDIM 100
#define ODIM 104

// workspace offsets (bytes), 256-aligned
#define OFF_WIH    32768u      // wih B-frags (16x16x32):  2*21*4*64*8*2  = 172032
#define OFF_WHH    204800u     // whh B-frags (16x16x32):  2*21*4*64*8*2  = 172032
#define OFF_BIASP  376832u     // bias (bih + bhh_{r,z}; bih_n): 2*384*4  = 3072
#define OFF_STMT   379904u     // stmt f16 [t*64+b][128]:    4096*128*2   = 1048576
#define OFF_POOL   1428480u    // pooled fp32: 2*64*128*4                 = 65536

__device__ inline f32x4 zero4() { f32x4 z = {0.f, 0.f, 0.f, 0.f}; return z; }

// minimal-op transcendentals (guaranteed v_exp/v_rcp, no ocml fixup chains)
__device__ inline float fast_exp2(float x) {
  float r; asm("v_exp_f32 %0, %1" : "=v"(r) : "v"(x)); return r;
}
__device__ inline float fast_rcp(float x) {
  float r; asm("v_rcp_f32 %0, %1" : "=v"(r) : "v"(x)); return r;
}
__device__ inline float sigmoid_f(float x) {        // 1/(1+e^-x)
  return fast_rcp(1.f + fast_exp2(x * -1.44269504f));
}
__device__ inline float tanh_f(float x) {           // 1 - 2/(1+e^(2x))
  float e = fast_exp2(x * 2.88539008f);
  return fmaf(fast_rcp(1.f + e), -2.f, 1.f);
}

// K3 LDS swizzle: read 2-way-free AND write conflict-free
#define HSWZ(row) ((((row) & 3) << 4) ^ (((row) & 12) << 3))

// ---------------------------------------------------------------------------
// K1: 512 blocks, each processes TWO 128-node tiles sequentially (8 trees).
//     W_lin->frag conversion done ONCE per block (halves total conv cost vs
//     1024 blocks). h-frag LDS write packed as b64 (4 contiguous f16).
//     Blocks 0-86 additionally run the gru weight prep slices.
//     Ancestor walk overlapped into the GEMM1 phase.
//     stmt stored in row' = t*64 + b order (tree g = b*64+t).
// ---------------------------------------------------------------------------
__global__ __launch_bounds__(256, 2) void astnn_tree(
    const int* __restrict__ node_ids, const int* __restrict__ parent,
    const float* __restrict__ emb, const float* __restrict__ W_lin,
    const float* __restrict__ b_lin,
    const float* __restrict__ wihf, const float* __restrict__ whhf,
    const float* __restrict__ bihf, const float* __restrict__ bhhf,
    const float* __restrict__ wihb, const float* __restrict__ whhb,
    const float* __restrict__ bihb, const float* __restrict__ bhhb,
    _Float16* __restrict__ wihfrag, _Float16* __restrict__ whhfrag,
    float* __restrict__ biasP, _Float16* __restrict__ stmt)
{
  __shared__ _Float16 ldsW[16384];   // 32KB: W_lin B-frags (built once)
  __shared__ _Float16 ldsA[16384];   // 32KB: emb tile (swizzled), reused for h-frags
  __shared__ int ldsPar[128];
  __shared__ unsigned ldsAnc[128];

  const int t = threadIdx.x, blk = blockIdx.x;
  const int w = t >> 6, l = t & 63;

  // ---- gru prep slice (blocks 0-86): wih/whh frags + bias, global-only ----
  if (blk < 87) {
    int gid = blk * 256 + t;                 // 0..22271
    if (gid < 10752) {
      // wih -> 16x16x32 B-frags: N per-section 112 (21 tiles), K=128
      int i = gid, ll = i & 63, kc = (i >> 6) & 3;
      int rest = i >> 8, nt = rest % 21, d = rest / 21;
      const float* wih = d ? wihb : wihf;
      int n = (nt << 4) + (ll & 15), s = n / 112, j = n - 112 * s;
      int kb = (kc << 5) + ((ll >> 4) << 3);
#pragma unroll
      for (int e = 0; e < 8; e++) {
        int k = kb + e;
        float v = (j < HDIM) ? wih[(s * HDIM + j) * CDIM + k] : 0.f;
        wihfrag[i * 8 + e] = (_Float16)v;
      }
    } else if (gid < 21504) {
      // whh -> 16x16x32 B-frags: K padded to 128; k==HDIM (s==2) carries bhh_n
      int i = gid - 10752, ll = i & 63, kc = (i >> 6) & 3;
      int rest = i >> 8, nt = rest % 21, d = rest / 21;
      const float* whh = d ? whhb : whhf;
      const float* bhh = d ? bhhb : bhhf;
      int n = (nt << 4) + (ll & 15), s = n / 112, j = n - 112 * s;
      int kb = (kc << 5) + ((ll >> 4) << 3);
#pragma unroll
      for (int e = 0; e < 8; e++) {
        int k = kb + e;
        float v = 0.f;
        if (j < HDIM) {
          if (k < HDIM) v = whh[(s * HDIM + j) * HDIM + k];
          else if (k == HDIM && s == 2) v = bhh[2 * HDIM + j];
        }
        whhfrag[i * 8 + e] = (_Float16)v;
      }
    } else {
      // biasP[d][384] = bih[g] + (s<2 ? bhh[g] : 0), pad = 0
      int i = gid - 21504, d = i / 384, col = i % 384, s = col >> 7, j = col & 127;
      const float* bih = d ? bihb : bihf;
      const float* bhh = d ? bhhb : bhhf;
      float v = 0.f;
      if (j < HDIM) { v = bih[s * HDIM + j]; if (s < 2) v += bhh[s * HDIM + j]; }
      biasP[i] = v;
    }
  }

  {  // W_lin -> 16x16x32 B-frags directly into ldsW (once per block, L2-hot)
#pragma unroll
    for (int i8 = 0; i8 < 8; i8++) {
      int fi = i8 * 256 + t;
      int ll = fi & 63, kc = (fi >> 6) & 3, nt = fi >> 8;
      int n = (nt << 4) + (ll & 15);
      int kb = (kc << 5) + ((ll >> 4) << 3);
      H8 u;
#pragma unroll
      for (int e = 0; e < 8; e++)
        u.h[e] = (_Float16)W_lin[(kb + e) * CDIM + n];
      *(float4*)&ldsW[fi * 8] = u.f;
    }
  }

#pragma unroll 1
  for (int half = 0; half < 2; ++half) {
    const int base = (blk * 2 + half) * 128;

    if (t < 128) ldsPar[t] = parent[base + t] & 31;  // trees 32-aligned globally

    {  // gather embedding rows -> f16, swizzled row-major [128][128]
      const int r = t >> 1, hf = t & 1;
      const int nid = node_ids[base + r];
      const float4* erow = (const float4*)(emb + (size_t)nid * EDIM) + hf * 16;
#pragma unroll
      for (int b2 = 0; b2 < 2; b2++) {
        float4 stage[8];
#pragma unroll
        for (int i = 0; i < 8; i++) stage[i] = erow[b2 * 8 + i];
#pragma unroll
        for (int c4 = 0; c4 < 4; c4++) {
          H8 u;
#pragma unroll
          for (int e = 0; e < 8; e++)
            u.h[e] = (_Float16)(((const float*)&stage[0])[c4 * 8 + e]);
          int c = b2 * 4 + c4;
          int addr = (r * 256 + hf * 128 + c * 16) ^ ((r & 7) << 4);
          *(float4*)((char*)ldsA + addr) = u.f;
        }
      }
    }
    __syncthreads();   // emb tile + ldsPar ready (also fences prev iter reads)

    // GEMM: h[128][128] = emb_tile @ W, wave w owns M-tiles 2w,2w+1
    f32x4 acc[2][8];
#pragma unroll
    for (int mt = 0; mt < 2; mt++)
#pragma unroll
      for (int nt = 0; nt < 8; nt++) acc[mt][nt] = zero4();
#pragma unroll
    for (int kc = 0; kc < 4; kc++) {
      half8 af[2];
#pragma unroll
      for (int mt = 0; mt < 2; mt++) {
        int row = (w * 2 + mt) * 16 + (l & 15);
        int addr = (row * 256 + (kc << 6) + ((l >> 4) << 4)) ^ ((row & 7) << 4);
        af[mt] = *(const half8*)((const char*)ldsA + addr);
      }
#pragma unroll
      for (int nt = 0; nt < 8; nt++) {
        half8 bf = *(const half8*)&ldsW[(((nt << 2) | kc) * 64 + l) * 8];
        acc[0][nt] = __builtin_amdgcn_mfma_f32_16x16x32_f16(af[0], bf, acc[0][nt], 0, 0, 0);
        acc[1][nt] = __builtin_amdgcn_mfma_f32_16x16x32_f16(af[1], bf, acc[1][nt], 0, 0, 0);
      }
    }
    // ancestor walk overlapped with GEMM1 drain (output needed only in GEMM2)
    if (t < 128) {
      int tree = t >> 5;
      unsigned mask = 0;
      int cur = t & 31;
#pragma unroll
      for (int it = 0; it < 11; ++it) { mask |= (1u << cur); cur = ldsPar[tree * 32 + cur]; }
      ldsAnc[t] = mask;
    }
    __syncthreads();  // emb-tile reads done; ldsA reused for h-fragments

    // write h (+b_lin) into 32x32x16 B-frag layout, PACKED b64 (4 f16/write)
#pragma unroll
    for (int mt = 0; mt < 2; mt++) {
      const int Mt = w * 2 + mt, tree = Mt >> 1, kc2 = Mt & 1;
      const int ebase = ((l >> 4) & 1) << 2;         // rowrem&7 base: 0 or 4
      const int l2hi = ((l >> 4) >> 1) << 5;         // rowrem>>3 term
#pragma unroll
      for (int nt = 0; nt < 8; nt++) {
        const float bl = b_lin[nt * 16 + (l & 15)];
        const int nt2 = nt >> 1;
        const int ncol = ((nt & 1) << 4) + (l & 15);
        half4v v;
#pragma unroll
        for (int reg = 0; reg < 4; reg++)
          v[reg] = (_Float16)(acc[mt][nt][reg] + bl);
        int idx = (((((tree << 2) + nt2) << 1) + kc2) * 64 + (l2hi + ncol)) * 8 + ebase;
        *(half4v*)&ldsA[idx] = v;
      }
    }
    __syncthreads();

    // per-tree subtree-sum: S[32][128] = anc(0/1) @ h (32x32x16), wave w = tree w
    {
      const int tree = w;
      half8 ancf[2];
#pragma unroll
      for (int kc2 = 0; kc2 < 2; kc2++) {
        H8 u;
#pragma unroll
        for (int e = 0; e < 8; e++) {
          int n = (kc2 << 4) + ((l >> 5) << 3) + e;
          unsigned m = ldsAnc[(tree << 5) + n];
          u.h[e] = (_Float16)(float)((m >> (l & 31)) & 1u);
        }
        ancf[kc2] = u.h;
      }
      f32x16 acc2[4];
#pragma unroll
      for (int nt2 = 0; nt2 < 4; nt2++)
#pragma unroll
        for (int e = 0; e < 16; e++) acc2[nt2][e] = 0.f;
#pragma unroll
      for (int nt2 = 0; nt2 < 4; nt2++)
#pragma unroll
        for (int kc2 = 0; kc2 < 2; kc2++) {
          half8 bf = *(const half8*)&ldsA[(((((tree << 2) + nt2) << 1) + kc2) * 64 + l) * 8];
          acc2[nt2] = __builtin_amdgcn_mfma_f32_32x32x16_f16(ancf[kc2], bf, acc2[nt2], 0, 0, 0);
        }
      // max-pool over the 32 node rows -> stmt[row'][c], row' = t*64 + b
#pragma unroll
      for (int nt2 = 0; nt2 < 4; nt2++) {
        float m1 = acc2[nt2][0];
#pragma unroll
        for (int e = 1; e < 16; e++) m1 = fmaxf(m1, acc2[nt2][e]);
        m1 = fmaxf(m1, __shfl_xor(m1, 32));
        if (l < 32) {
          int g = (blk * 2 + half) * 4 + tree;       // tree = b*64 + t
          int rowp = (g & 63) * 64 + (g >> 6);       // row' = t*64 + b
          stmt[(size_t)rowp * CDIM + (nt2 << 5) + l] = (_Float16)m1;
        }
      }
    }
    __syncthreads();   // protect ldsA/ldsPar before next tile's gather
  }
}

// ---------------------------------------------------------------------------
// K3: bidirectional GRU with fused input GEMM, software-pipelined one step.
//     EXACT r13 form (pooled-store epilogue; FC stays a separate kernel —
//     fusing it degraded the loop's codegen, r11/r12 vs r13 A/B).
//     Grid (4 mb, 2 dirs), 7 waves. bhh_n via h col 100 = 1.0 carrier.
// ---------------------------------------------------------------------------
__global__ __launch_bounds__(448) void astnn_gru(
    const _Float16* __restrict__ whhfrag, const _Float16* __restrict__ wihfrag,
    const _Float16* __restrict__ stmt, const float* __restrict__ biasP,
    float* __restrict__ pooled)
{
  __shared__ _Float16 hlds[4096];  // 2 x (16 rows x 128 cols f16, swizzled)
  const int t = threadIdx.x, w = t >> 6, l = t & 63;
  const int mb = blockIdx.x, dir = blockIdx.y;
  for (int i = t; i < 512; i += 448)          // zero BOTH buffers
    ((float4*)hlds)[i] = make_float4(0.f, 0.f, 0.f, 0.f);
  __syncthreads();
  if (t < 32) {                               // h col 100 = 1.0 (bhh_n carrier)
    int row = t & 15, buf = t >> 4;
    int addr = ((row * 256 + 200) ^ HSWZ(row)) + (buf << 12);
    *(_Float16*)((char*)hlds + addr) = (_Float16)1.0f;
  }

  const int j = (w << 4) + (l & 15);
  const bool jv = (j < HDIM);
  const int rloc = (l >> 4) << 2;             // local row base: 0,4,8,12
  const int grow = (mb << 4) + rloc;          // global batch row base

  // hoisted LDS addresses (swizzle HSWZ)
  int raddr[4], waddr[4];
  {
    int row = l & 15;
#pragma unroll
    for (int kc = 0; kc < 4; kc++)
      raddr[kc] = (row * 256 + (kc << 6) + ((l >> 4) << 4)) ^ HSWZ(row);
#pragma unroll
    for (int reg = 0; reg < 4; reg++) {
      int rw = rloc + reg;
      waddr[reg] = (rw * 256 + (j << 1)) ^ HSWZ(rw);
    }
  }

  // weight B-frags: whh (hidden) and wih (input), same frag geometry
  half8 bfr[3][4], bfw[3][4];
  {
    const half8* wfh = (const half8*)whhfrag + dir * 5376;
    const half8* wfi = (const half8*)wihfrag + dir * 5376;
#pragma unroll
    for (int s = 0; s < 3; s++)
#pragma unroll
      for (int kc = 0; kc < 4; kc++) {
        int idx = (((s * 7 + w) << 2) + kc) * 64 + l;
        bfr[s][kc] = wfh[idx];
        bfw[s][kc] = wfi[idx];
      }
  }
  const float bias0 = biasP[dir * 384 + j];
  const float bias1 = biasP[dir * 384 + 128 + j];
  const float bias2 = biasP[dir * 384 + 256 + j];

  // stmt slab loads: lane-fixed byte offsets + SALU-stepped t pointer
  int soff[4];
#pragma unroll
  for (int kc = 0; kc < 4; kc++)
    soff[kc] = (((mb << 4) + (l & 15)) * 256) + (kc << 6) + ((l >> 4) << 4);
  const ptrdiff_t sstep = dir ? -16384 : 16384;   // 64 rows * 256B per t
  const char* sbase = (const char*)stmt + (size_t)(dir ? 63 : 0) * 16384;

  half8 sfA[4], sfB[4];
#pragma unroll
  for (int kc = 0; kc < 4; kc++) sfA[kc] = *(const half8*)(sbase + soff[kc]);
  const char* spre = sbase + sstep;
#pragma unroll
  for (int kc = 0; kc < 4; kc++) sfB[kc] = *(const half8*)(spre + soff[kc]);
  spre += sstep;

  // prologue: giA = bias + wih @ stmt[t0]
  f32x4 giA[3], giB[3];
  giA[0] = f32x4{bias0, bias0, bias0, bias0};
  giA[1] = f32x4{bias1, bias1, bias1, bias1};
  giA[2] = f32x4{bias2, bias2, bias2, bias2};
#pragma unroll
  for (int kc = 0; kc < 4; kc++) {
    giA[0] = __builtin_amdgcn_mfma_f32_16x16x32_f16(sfA[kc], bfw[0][kc], giA[0], 0, 0, 0);
    giA[1] = __builtin_amdgcn_mfma_f32_16x16x32_f16(sfA[kc], bfw[1][kc], giA[1], 0, 0, 0);
    giA[2] = __builtin_amdgcn_mfma_f32_16x16x32_f16(sfA[kc], bfw[2][kc], giA[2], 0, 0, 0);
  }

  float hreg[4], pool[4];
#pragma unroll
  for (int i = 0; i < 4; i++) { hreg[i] = 0.f; pool[i] = -3.0e38f; }
  __syncthreads();

  // GIC: gi consumed this step (copied into fresh accs — NOT in-place).
  // GIN: gi computed for next step from SFsrc. SFdst: prefetch target.
#define GRU_BODY(GIC, GIN, SFsrc, SFdst, ROFF, WOFF, CN, PF)                    \
  {                                                                             \
    half8 afh[4];                                                               \
    _Pragma("unroll")                                                           \
    for (int kc = 0; kc < 4; kc++)                                              \
      afh[kc] = *(const half8*)((const char*)hlds + raddr[kc] + (ROFF));        \
    f32x4 acc0 = GIC[0], acc1 = GIC[1];                                         \
    f32x4 acc2i = GIC[2], acc2h = zero4();                                      \
    _Pragma("unroll")  /* critical whh chain FIRST */                           \
    for (int kc = 0; kc < 4; kc++) {                                            \
      acc0  = __builtin_amdgcn_mfma_f32_16x16x32_f16(afh[kc], bfr[0][kc], acc0, 0, 0, 0); \
      acc1  = __builtin_amdgcn_mfma_f32_16x16x32_f16(afh[kc], bfr[1][kc], acc1, 0, 0, 0); \
      acc2h = __builtin_amdgcn_mfma_f32_16x16x32_f16(afh[kc], bfr[2][kc], acc2h, 0, 0, 0);\
    }                                                                           \
    if (CN) {  /* independent next-step gi chain: fills whh->gates latency */   \
      GIN[0] = f32x4{bias0, bias0, bias0, bias0};                               \
      GIN[1] = f32x4{bias1, bias1, bias1, bias1};                               \
      GIN[2] = f32x4{bias2, bias2, bias2, bias2};                               \
      _Pragma("unroll")                                                         \
      for (int kc = 0; kc < 4; kc++) {                                          \
        GIN[0] = __builtin_amdgcn_mfma_f32_16x16x32_f16(SFsrc[kc], bfw[0][kc], GIN[0], 0, 0, 0); \
        GIN[1] = __builtin_amdgcn_mfma_f32_16x16x32_f16(SFsrc[kc], bfw[1][kc], GIN[1], 0, 0, 0); \
        GIN[2] = __builtin_amdgcn_mfma_f32_16x16x32_f16(SFsrc[kc], bfw[2][kc], GIN[2], 0, 0, 0); \
      }                                                                         \
    }                                                                           \
    if (PF) {                                                                   \
      SFdst[0] = *(const half8*)(spre + soff[0]);                               \
      SFdst[1] = *(const half8*)(spre + soff[1]);                               \
      SFdst[2] = *(const half8*)(spre + soff[2]);                               \
      SFdst[3] = *(const half8*)(spre + soff[3]);                               \
      spre += sstep;                                                            \
    }                                                                           \
    _Pragma("unroll")                                                           \
    for (int reg = 0; reg < 4; reg++) {                                         \
      float r = sigmoid_f(acc0[reg]);                                           \
      float z = sigmoid_f(acc1[reg]);                                           \
      float n = tanh_f(fmaf(r, acc2h[reg], acc2i[reg]));                        \
      float hn = n + z * (hreg[reg] - n);                                       \
      hreg[reg] = hn;                                                           \
      pool[reg] = fmaxf(pool[reg], hn);                                         \
      if (jv)                                                                   \
        *(_Float16*)((char*)hlds + waddr[reg] + (WOFF)) = (_Float16)hn;         \
    }                                                                           \
    asm volatile("s_waitcnt lgkmcnt(0)" ::: "memory");                          \
    __builtin_amdgcn_s_barrier();                                               \
    __builtin_amdgcn_sched_barrier(0);                                          \
  }

#pragma unroll 1
  for (int it = 0; it < 31; ++it) {
    GRU_BODY(giA, giB, sfB, sfA, 0, 4096, 1, 1)       // even step 2it
    GRU_BODY(giB, giA, sfA, sfB, 4096, 0, 1, 1)       // odd  step 2it+1
  }
  GRU_BODY(giA, giB, sfB, sfA, 0, 4096, 1, 0)         // step 62
  GRU_BODY(giB, giA, sfA, sfB, 4096, 0, 0, 0)         // step 63
#undef GRU_BODY

  if (jv) {
#pragma unroll
    for (int reg = 0; reg < 4; reg++)
      pooled[((size_t)dir << 13) + ((size_t)(grow + reg) << 7) + j] = pool[reg];
  }
}

// ---------------------------------------------------------------------------
// K4: out[b][o] = [pooled_f | pooled_b] @ fc_w + fc_b
// ---------------------------------------------------------------------------
__global__ __launch_bounds__(128) void astnn_fc(
    const float* __restrict__ pooled, const float* __restrict__ fc_w,
    const float* __restrict__ fc_b, float* __restrict__ out)
{
  __shared__ float p[200];
  const int b = blockIdx.x, t = threadIdx.x;
  for (int i = t; i < 200; i += 128) {
    int d = i / 100, jj = i - d * 100;
    p[i] = pooled[((size_t)d << 13) + (b << 7) + jj];
  }
  __syncthreads();
  if (t < ODIM) {
    float a = fc_b[t];
#pragma unroll 8
    for (int k = 0; k < 200; k++) a = fmaf(p[k], fc_w[k * ODIM + t], a);
    out[b * ODIM + t] = a;
  }
}

// ---------------------------------------------------------------------------
extern "C" void kernel_launch(void* const* d_in, const int* in_sizes, int n_in,
                              void* d_out, int out_size, void* d_ws, size_t ws_size,
                              hipStream_t stream)
{
  const int* node_ids = (const int*)d_in[0];
  const int* parent   = (const int*)d_in[1];
  // d_in[2]=level, d_in[3]=tree_id: unused (decreasing-index order suffices)
  const float* emb    = (const float*)d_in[4];
  const float* W_lin  = (const float*)d_in[5];
  const float* b_lin  = (const float*)d_in[6];
  const float* wihf   = (const float*)d_in[7];
  const float* whhf   = (const float*)d_in[8];
  const float* bihf   = (const float*)d_in[9];
  const float* bhhf   = (const float*)d_in[10];
  const float* wihb   = (const float*)d_in[11];
  const float* whhb   = (const float*)d_in[12];
  const float* bihb   = (const float*)d_in[13];
  const float* bhhb   = (const float*)d_in[14];
  const float* fc_w   = (const float*)d_in[15];
  const float* fc_b   = (const float*)d_in[16];

  char* ws = (char*)d_ws;
  _Float16* wihfrag = (_Float16*)(ws + OFF_WIH);
  _Float16* whhfrag = (_Float16*)(ws + OFF_WHH);
  float* biasP      = (float*)(ws + OFF_BIASP);
  _Float16* stmt    = (_Float16*)(ws + OFF_STMT);
  float* pooled     = (float*)(ws + OFF_POOL);
  float* out        = (float*)d_out;

  astnn_tree<<<512, 256, 0, stream>>>(node_ids, parent, emb, W_lin, b_lin,
                                      wihf, whhf, bihf, bhhf,
                                      wihb, whhb, bihb, bhhb,
                                      wihfrag, whhfrag, biasP, stmt);
  astnn_gru<<<dim3(4, 2), 448, 0, stream>>>(whhfrag, wihfrag, stmt, biasP, pooled);
  astnn_fc<<<64, 128, 0, stream>>>(pooled, fc_w, fc_b, out);
}